// Round 1
// baseline (91.374 us; speedup 1.0000x reference)
//
#include <hip/hip_runtime.h>
#include <float.h>

// Problem constants (from reference setup_inputs):
//   input: (1, C=64, 48, 48, 48) fp32
//   rois:  (1, N=16, 7) int32  [batch, sx, sy, sz, ex, ey, ez]
//   out:   (N, C, 4, 4, 4) fp32 = 65536 elements
#define NC 64
#define DIM 48
#define NROI 16
#define NOUT (NROI * NC * 4 * 4 * 4)

__global__ __launch_bounds__(256) void roipool3d_kernel(
    const float* __restrict__ feat,   // (C, 48, 48, 48)
    const int*   __restrict__ rois,   // (N, 7)
    float*       __restrict__ out)    // (N, C, 4, 4, 4)
{
    int idx = blockIdx.x * 256 + threadIdx.x;
    if (idx >= NOUT) return;

    int k = idx & 3;
    int j = (idx >> 2) & 3;
    int i = (idx >> 4) & 3;
    int c = (idx >> 6) & (NC - 1);
    int n = idx >> 12;

    // ROI params: wave-uniform (64 consecutive idx share n,c)
    const int* r = rois + n * 7;
    int sx = r[1], sy = r[2], sz = r[3];
    int lx = r[4] + 1 - sx;
    int ly = r[5] + 1 - sy;
    int lz = r[6] + 1 - sz;

    // PyTorch adaptive-pool bin bounds: [s + floor(i*L/4), s + ceil((i+1)*L/4))
    int bx0 = sx + (i * lx) >> 2;        // careful: precedence — see below
    // (re-compute explicitly to avoid precedence bugs)
    bx0 = sx + ((i * lx) >> 2);
    int bx1 = sx + (((i + 1) * lx + 3) >> 2);
    int by0 = sy + ((j * ly) >> 2);
    int by1 = sy + (((j + 1) * ly + 3) >> 2);
    int bz0 = sz + ((k * lz) >> 2);
    int bz1 = sz + (((k + 1) * lz + 3) >> 2);

    const float* base = feat + (size_t)c * (DIM * DIM * DIM);

    float m = -FLT_MAX;
    for (int x = bx0; x < bx1; ++x) {
        for (int y = by0; y < by1; ++y) {
            const float* row = base + x * (DIM * DIM) + y * DIM;
            int z = bz0;
            // unroll-by-4: 4 independent loads in flight per iteration
            for (; z + 3 < bz1; z += 4) {
                float a0 = row[z];
                float a1 = row[z + 1];
                float a2 = row[z + 2];
                float a3 = row[z + 3];
                m = fmaxf(m, fmaxf(fmaxf(a0, a1), fmaxf(a2, a3)));
            }
            for (; z < bz1; ++z) m = fmaxf(m, row[z]);
        }
    }
    out[idx] = m;
}

extern "C" void kernel_launch(void* const* d_in, const int* in_sizes, int n_in,
                              void* d_out, int out_size, void* d_ws, size_t ws_size,
                              hipStream_t stream) {
    const float* feat = (const float*)d_in[0];
    const int*   rois = (const int*)d_in[1];
    float*       out  = (float*)d_out;

    dim3 grid((NOUT + 255) / 256);
    dim3 block(256);
    roipool3d_kernel<<<grid, block, 0, stream>>>(feat, rois, out);
}

// Round 2
// 75.634 us; speedup vs baseline: 1.2081x; 1.2081x over previous
//
#include <hip/hip_runtime.h>
#include <float.h>

// Problem constants (from reference setup_inputs):
//   input: (1, C=64, 48, 48, 48) fp32
//   rois:  (1, N=16, 7) int32  [batch, sx, sy, sz, ex, ey, ez]
//   out:   (N, C, 4, 4, 4) fp32 = 65536 elements
#define NC 64
#define DIM 48
#define NROI 16

// One block per (n, c): blockIdx.x = n*64 + c  (1024 blocks, 256 threads).
// Each output bin (4x4x4 = 64 per block) is computed by 4 lanes: lane p of
// the bin's quad takes every 4th (x,y) row of the bin's sub-box, scans the
// contiguous z-run, then the quad reduces with __shfl_xor(1|2).
// -> 4096 waves total (16 waves/CU) vs 1024 in round 1, and the per-thread
//    dependent-load chain shrinks ~4x.
__global__ __launch_bounds__(256) void roipool3d_kernel(
    const float* __restrict__ feat,   // (C, 48, 48, 48)
    const int*   __restrict__ rois,   // (N, 7)
    float*       __restrict__ out)    // (N, C, 4, 4, 4)
{
    int t = threadIdx.x;
    int bin = t >> 2;          // 0..63 -> (i,j,k)
    int p   = t & 3;           // quad lane
    int c = blockIdx.x & (NC - 1);
    int n = blockIdx.x >> 6;

    int k = bin & 3;
    int j = (bin >> 2) & 3;
    int i = bin >> 4;

    // ROI params: block-uniform -> scalar loads
    const int* r = rois + n * 7;
    int sx = r[1], sy = r[2], sz = r[3];
    int lx = r[4] + 1 - sx;
    int ly = r[5] + 1 - sy;
    int lz = r[6] + 1 - sz;

    // PyTorch adaptive-pool bin: [s + floor(i*L/4), s + ceil((i+1)*L/4))
    int bx0 = sx + ((i * lx) >> 2);
    int bx1 = sx + (((i + 1) * lx + 3) >> 2);
    int by0 = sy + ((j * ly) >> 2);
    int by1 = sy + (((j + 1) * ly + 3) >> 2);
    int bz0 = sz + ((k * lz) >> 2);
    int bz1 = sz + (((k + 1) * lz + 3) >> 2);

    int nx = bx1 - bx0;
    int ny = by1 - by0;
    int nrows = nx * ny;

    const float* base = feat + (size_t)c * (DIM * DIM * DIM);

    // Two accumulators to shorten the fmax dependency chain
    float m0 = -FLT_MAX, m1 = -FLT_MAX;
    for (int rr = p; rr < nrows; rr += 4) {
        int x = bx0 + rr / ny;
        int y = by0 + rr % ny;
        const float* row = base + x * (DIM * DIM) + y * DIM;
        int z = bz0;
        for (; z + 1 < bz1; z += 2) {
            m0 = fmaxf(m0, row[z]);
            m1 = fmaxf(m1, row[z + 1]);
        }
        if (z < bz1) m0 = fmaxf(m0, row[z]);
    }
    float m = fmaxf(m0, m1);

    // quad reduce (lanes of a bin are consecutive)
    m = fmaxf(m, __shfl_xor(m, 1));
    m = fmaxf(m, __shfl_xor(m, 2));

    if (p == 0) out[(blockIdx.x << 6) + bin] = m;
}

extern "C" void kernel_launch(void* const* d_in, const int* in_sizes, int n_in,
                              void* d_out, int out_size, void* d_ws, size_t ws_size,
                              hipStream_t stream) {
    const float* feat = (const float*)d_in[0];
    const int*   rois = (const int*)d_in[1];
    float*       out  = (float*)d_out;

    roipool3d_kernel<<<dim3(NROI * NC), dim3(256), 0, stream>>>(feat, rois, out);
}